// Round 1
// baseline (4339.020 us; speedup 1.0000x reference)
//
#include <hip/hip_runtime.h>
#include <math.h>

#define NEG_SLOPE 0.2f

__device__ __forceinline__ unsigned enc_f32(float f) {
    unsigned u = __float_as_uint(f);
    return (u & 0x80000000u) ? ~u : (u | 0x80000000u);
}
__device__ __forceinline__ float dec_f32(unsigned s) {
    unsigned u = (s & 0x80000000u) ? (s ^ 0x80000000u) : ~s;
    return __uint_as_float(u);
}

// K0: argmax over V features + embedding gather -> h0 [N, D]. One wave (64 lanes) per node.
__global__ void k_embed(const float* __restrict__ x, const float* __restrict__ emb,
                        float* __restrict__ h0, int N, int V, int D) {
    int wave = (blockIdx.x * blockDim.x + threadIdx.x) >> 6;
    int lane = threadIdx.x & 63;
    if (wave >= N) return;
    const float* row = x + (long long)wave * V;
    float bv = -INFINITY;
    int bi = 0x7fffffff;
    for (int j = lane; j < V; j += 64) {
        float v = row[j];
        if (v > bv || (v == bv && j < bi)) { bv = v; bi = j; }
    }
    for (int off = 32; off > 0; off >>= 1) {
        float ov = __shfl_down(bv, off, 64);
        int   oi = __shfl_down(bi, off, 64);
        if (ov > bv || (ov == bv && oi < bi)) { bv = ov; bi = oi; }
    }
    bi = __shfl(bi, 0, 64);
    const float* er = emb + (long long)bi * D;
    float* hr = h0 + (long long)wave * D;
    for (int f = lane; f < D; f += 64) hr[f] = er[f];
}

// K1: h_t = h_in @ W ; asrc = h_t . a_src ; adst = h_t . a_dst. One thread per node.
template <int FIN, int FOUT>
__global__ void k_transform(const float* __restrict__ h_in, const float* __restrict__ W,
                            const float* __restrict__ a_src, const float* __restrict__ a_dst,
                            float* __restrict__ h_t, float* __restrict__ asrc,
                            float* __restrict__ adst, int N) {
    __shared__ float sW[FIN * FOUT];
    __shared__ float sa[FOUT], sd[FOUT];
    for (int i = threadIdx.x; i < FIN * FOUT; i += blockDim.x) sW[i] = W[i];
    if (threadIdx.x < FOUT) { sa[threadIdx.x] = a_src[threadIdx.x]; sd[threadIdx.x] = a_dst[threadIdx.x]; }
    __syncthreads();
    int n = blockIdx.x * blockDim.x + threadIdx.x;
    if (n >= N) return;
    float acc[FOUT];
#pragma unroll
    for (int f = 0; f < FOUT; f++) acc[f] = 0.f;
    const float* hr = h_in + (long long)n * FIN;
    for (int k = 0; k < FIN; k++) {
        float v = hr[k];
#pragma unroll
        for (int f = 0; f < FOUT; f++) acc[f] += v * sW[k * FOUT + f];
    }
    float s1 = 0.f, s2 = 0.f;
    float* tr = h_t + (long long)n * FOUT;
#pragma unroll
    for (int f = 0; f < FOUT; f++) {
        tr[f] = acc[f];
        s1 += acc[f] * sa[f];
        s2 += acc[f] * sd[f];
    }
    asrc[n] = s1;
    adst[n] = s2;
}

// K2: per-edge e = leaky_relu(asrc[src]+adst[dst]); segment max via encoded atomicMax.
__global__ void k_edge_max(const int* __restrict__ esrc, const int* __restrict__ edst,
                           int E, int NE, const float* __restrict__ asrc,
                           const float* __restrict__ adst, float* __restrict__ e,
                           unsigned* __restrict__ m_enc) {
    int i = blockIdx.x * blockDim.x + threadIdx.x;
    if (i >= NE) return;
    int s, d;
    if (i < E) { s = esrc[i]; d = edst[i]; } else { s = d = i - E; }
    float v = asrc[s] + adst[d];
    v = (v >= 0.f) ? v : NEG_SLOPE * v;
    e[i] = v;
    atomicMax(m_enc + d, enc_f32(v));
}

// K3: p = exp(e - m[dst]); denom[dst] += p; store p in-place.
__global__ void k_edge_exp(const int* __restrict__ edst, int E, int NE,
                           float* __restrict__ e, const unsigned* __restrict__ m_enc,
                           float* __restrict__ denom) {
    int i = blockIdx.x * blockDim.x + threadIdx.x;
    if (i >= NE) return;
    int d = (i < E) ? edst[i] : i - E;
    float p = expf(e[i] - dec_f32(m_enc[d]));
    e[i] = p;
    atomicAdd(denom + d, p);
}

// K4: out[dst] += (p/denom[dst]) * h_t[src]
template <int FOUT>
__global__ void k_edge_agg(const int* __restrict__ esrc, const int* __restrict__ edst,
                           int E, int NE, const float* __restrict__ e,
                           const float* __restrict__ denom, const float* __restrict__ h_t,
                           float* __restrict__ acc) {
    int i = blockIdx.x * blockDim.x + threadIdx.x;
    if (i >= NE) return;
    int s, d;
    if (i < E) { s = esrc[i]; d = edst[i]; } else { s = d = i - E; }
    float alpha = e[i] / fmaxf(denom[d], 1e-16f);
    const float* hr = h_t + (long long)s * FOUT;
    float* ar = acc + (long long)d * FOUT;
#pragma unroll
    for (int f = 0; f < FOUT; f++) atomicAdd(ar + f, alpha * hr[f]);
}

// K5: x = x + b[f]; optional relu
template <int FOUT, bool RELU>
__global__ void k_bias_act(float* __restrict__ h, const float* __restrict__ b, int total) {
    int i = blockIdx.x * blockDim.x + threadIdx.x;
    if (i >= total) return;
    float v = h[i] + b[i % FOUT];
    h[i] = RELU ? fmaxf(v, 0.f) : v;
}

// K6: one block per graph; binary-search node range in sorted batch; mean-pool + b3 + softmax.
__global__ void k_pool(const float* __restrict__ h3, const int* __restrict__ batch,
                       const float* __restrict__ b3, float* __restrict__ out, int N, int C) {
    int g = blockIdx.x;
    int lo = 0, hi = N;
    while (lo < hi) { int mid = (lo + hi) >> 1; if (batch[mid] < g) lo = mid + 1; else hi = mid; }
    int start = lo;
    hi = N;
    while (lo < hi) { int mid = (lo + hi) >> 1; if (batch[mid] < g + 1) lo = mid + 1; else hi = mid; }
    int end = lo;

    float sum[16];
    for (int f = 0; f < C; f++) sum[f] = 0.f;
    for (int n = start + threadIdx.x; n < end; n += blockDim.x) {
        const float* r = h3 + (long long)n * C;
        for (int f = 0; f < C; f++) sum[f] += r[f];
    }
    __shared__ float red[256 * 16];
    for (int f = 0; f < C; f++) red[threadIdx.x * 16 + f] = sum[f];
    __syncthreads();
    for (int str = blockDim.x / 2; str > 0; str >>= 1) {
        if ((int)threadIdx.x < str)
            for (int f = 0; f < C; f++) red[threadIdx.x * 16 + f] += red[(threadIdx.x + str) * 16 + f];
        __syncthreads();
    }
    if (threadIdx.x == 0) {
        float cnt = fmaxf((float)(end - start), 1.f);
        float vals[16];
        float mx = -INFINITY;
        for (int f = 0; f < C; f++) { vals[f] = red[f] / cnt + b3[f]; mx = fmaxf(mx, vals[f]); }
        float se = 0.f;
        for (int f = 0; f < C; f++) { vals[f] = expf(vals[f] - mx); se += vals[f]; }
        for (int f = 0; f < C; f++) out[(long long)g * C + f] = vals[f] / se;
    }
}

extern "C" void kernel_launch(void* const* d_in, const int* in_sizes, int n_in,
                              void* d_out, int out_size, void* d_ws, size_t ws_size,
                              hipStream_t stream) {
    const float* x    = (const float*)d_in[0];
    const int*   eidx = (const int*)d_in[1];
    const int*   batch= (const int*)d_in[2];
    const float* emb  = (const float*)d_in[3];
    const float* W1   = (const float*)d_in[4];
    const float* as1  = (const float*)d_in[5];
    const float* ad1  = (const float*)d_in[6];
    const float* b1   = (const float*)d_in[7];
    const float* W2   = (const float*)d_in[8];
    const float* as2  = (const float*)d_in[9];
    const float* ad2  = (const float*)d_in[10];
    const float* b2   = (const float*)d_in[11];
    const float* W3   = (const float*)d_in[12];
    const float* as3  = (const float*)d_in[13];
    const float* ad3  = (const float*)d_in[14];
    const float* b3   = (const float*)d_in[15];

    const int H = in_sizes[5];          // 16
    const int C = in_sizes[13];         // 10
    const int D = in_sizes[4] / H;      // 50
    const int V = in_sizes[3] / D;      // 128
    const int N = in_sizes[0] / V;      // 100000
    const int E = in_sizes[1] / 2;      // 1600000
    const int NE = E + N;
    const int G = out_size / C;         // 512
    const int* esrc = eidx;
    const int* edst = eidx + E;

    // workspace carve-up (256B aligned)
    char* w = (char*)d_ws;
    auto carve = [&](size_t bytes) {
        char* p = w;
        w += (bytes + 255) & ~(size_t)255;
        return p;
    };
    float*    h0    = (float*)carve((size_t)N * D * 4);
    float*    hT    = (float*)carve((size_t)N * H * 4);
    float*    X0    = (float*)carve((size_t)N * H * 4);
    float*    X1    = (float*)carve((size_t)N * H * 4);
    float*    asrc  = (float*)carve((size_t)N * 4);
    float*    adst  = (float*)carve((size_t)N * 4);
    unsigned* m_enc = (unsigned*)carve((size_t)N * 4);
    float*    denom = (float*)carve((size_t)N * 4);
    float*    ebuf  = (float*)carve((size_t)NE * 4);
    (void)ws_size; (void)n_in; (void)G;

    const int BT = 256;
    dim3 blk(BT);
    int gN  = (N + BT - 1) / BT;
    int gNE = (NE + BT - 1) / BT;
    int gEmb = (N + 3) / 4;  // 4 waves per block

    // K0: embedding
    k_embed<<<gEmb, blk, 0, stream>>>(x, emb, h0, N, V, D);

    // ---- layer 1: 50 -> 16, relu ----
    hipMemsetAsync(m_enc, 0, (size_t)N * 4, stream);
    hipMemsetAsync(denom, 0, (size_t)N * 4, stream);
    hipMemsetAsync(X0, 0, (size_t)N * H * 4, stream);
    k_transform<50, 16><<<gN, blk, 0, stream>>>(h0, W1, as1, ad1, hT, asrc, adst, N);
    k_edge_max<<<gNE, blk, 0, stream>>>(esrc, edst, E, NE, asrc, adst, ebuf, m_enc);
    k_edge_exp<<<gNE, blk, 0, stream>>>(edst, E, NE, ebuf, m_enc, denom);
    k_edge_agg<16><<<gNE, blk, 0, stream>>>(esrc, edst, E, NE, ebuf, denom, hT, X0);
    k_bias_act<16, true><<<(N * 16 + BT - 1) / BT, blk, 0, stream>>>(X0, b1, N * 16);

    // ---- layer 2: 16 -> 16, relu ----
    hipMemsetAsync(m_enc, 0, (size_t)N * 4, stream);
    hipMemsetAsync(denom, 0, (size_t)N * 4, stream);
    hipMemsetAsync(X1, 0, (size_t)N * H * 4, stream);
    k_transform<16, 16><<<gN, blk, 0, stream>>>(X0, W2, as2, ad2, hT, asrc, adst, N);
    k_edge_max<<<gNE, blk, 0, stream>>>(esrc, edst, E, NE, asrc, adst, ebuf, m_enc);
    k_edge_exp<<<gNE, blk, 0, stream>>>(edst, E, NE, ebuf, m_enc, denom);
    k_edge_agg<16><<<gNE, blk, 0, stream>>>(esrc, edst, E, NE, ebuf, denom, hT, X1);
    k_bias_act<16, true><<<(N * 16 + BT - 1) / BT, blk, 0, stream>>>(X1, b2, N * 16);

    // ---- layer 3: 16 -> 10, no relu (b3 folded into pooling) ----
    hipMemsetAsync(m_enc, 0, (size_t)N * 4, stream);
    hipMemsetAsync(denom, 0, (size_t)N * 4, stream);
    hipMemsetAsync(X0, 0, (size_t)N * C * 4, stream);
    k_transform<16, 10><<<gN, blk, 0, stream>>>(X1, W3, as3, ad3, hT, asrc, adst, N);
    k_edge_max<<<gNE, blk, 0, stream>>>(esrc, edst, E, NE, asrc, adst, ebuf, m_enc);
    k_edge_exp<<<gNE, blk, 0, stream>>>(edst, E, NE, ebuf, m_enc, denom);
    k_edge_agg<10><<<gNE, blk, 0, stream>>>(esrc, edst, E, NE, ebuf, denom, hT, X0);

    // K6: pool + softmax
    k_pool<<<G, blk, 0, stream>>>(X0, batch, b3, (float*)d_out, N, C);
}

// Round 2
// 622.659 us; speedup vs baseline: 6.9685x; 6.9685x over previous
//
#include <hip/hip_runtime.h>
#include <math.h>

#define NEG_SLOPE 0.2f

// ---------------- K0: argmax over V features + embedding gather ----------------
__global__ void k_embed(const float* __restrict__ x, const float* __restrict__ emb,
                        float* __restrict__ h0, int N, int V, int D) {
    int wave = (blockIdx.x * blockDim.x + threadIdx.x) >> 6;
    int lane = threadIdx.x & 63;
    if (wave >= N) return;
    const float* row = x + (long long)wave * V;
    float bv = -INFINITY;
    int bi = 0x7fffffff;
    for (int j = lane; j < V; j += 64) {
        float v = row[j];
        if (v > bv || (v == bv && j < bi)) { bv = v; bi = j; }
    }
    for (int off = 32; off > 0; off >>= 1) {
        float ov = __shfl_down(bv, off, 64);
        int   oi = __shfl_down(bi, off, 64);
        if (ov > bv || (ov == bv && oi < bi)) { bv = ov; bi = oi; }
    }
    bi = __shfl(bi, 0, 64);
    const float* er = emb + (long long)bi * D;
    float* hr = h0 + (long long)wave * D;
    for (int f = lane; f < D; f += 64) hr[f] = er[f];
}

// ---------------- K1: dense transform + attention scalars ----------------
template <int FIN, int FOUT>
__global__ void k_transform(const float* __restrict__ h_in, const float* __restrict__ W,
                            const float* __restrict__ a_src, const float* __restrict__ a_dst,
                            float* __restrict__ h_t, float* __restrict__ asrc,
                            float* __restrict__ adst, int N) {
    __shared__ float sW[FIN * FOUT];
    __shared__ float sa[FOUT], sd[FOUT];
    for (int i = threadIdx.x; i < FIN * FOUT; i += blockDim.x) sW[i] = W[i];
    if (threadIdx.x < FOUT) { sa[threadIdx.x] = a_src[threadIdx.x]; sd[threadIdx.x] = a_dst[threadIdx.x]; }
    __syncthreads();
    int n = blockIdx.x * blockDim.x + threadIdx.x;
    if (n >= N) return;
    float acc[FOUT];
#pragma unroll
    for (int f = 0; f < FOUT; f++) acc[f] = 0.f;
    const float* hr = h_in + (long long)n * FIN;
    for (int k = 0; k < FIN; k++) {
        float v = hr[k];
#pragma unroll
        for (int f = 0; f < FOUT; f++) acc[f] += v * sW[k * FOUT + f];
    }
    float s1 = 0.f, s2 = 0.f;
    float* tr = h_t + (long long)n * FOUT;
#pragma unroll
    for (int f = 0; f < FOUT; f++) {
        tr[f] = acc[f];
        s1 += acc[f] * sa[f];
        s2 += acc[f] * sd[f];
    }
    asrc[n] = s1;
    adst[n] = s2;
}

// ---------------- CSR build (dst-grouped), self-loops handled implicitly ----------------
__global__ void k_hist(const int* __restrict__ edst, int E, int* __restrict__ counts) {
    int i = blockIdx.x * blockDim.x + threadIdx.x;
    if (i < E) atomicAdd(counts + edst[i], 1);
}

// per-block exclusive scan of 256 counts; block totals out
__global__ void k_scan1(const int* __restrict__ counts, int* __restrict__ excl,
                        int* __restrict__ bsums, int N) {
    __shared__ int s[256];
    int i = blockIdx.x * 256 + threadIdx.x;
    int v = (i < N) ? counts[i] : 0;
    s[threadIdx.x] = v;
    __syncthreads();
    for (int off = 1; off < 256; off <<= 1) {
        int t = (threadIdx.x >= (unsigned)off) ? s[threadIdx.x - off] : 0;
        __syncthreads();
        s[threadIdx.x] += t;
        __syncthreads();
    }
    if (i < N) excl[i] = s[threadIdx.x] - v;
    if (threadIdx.x == 255) bsums[blockIdx.x] = s[255];
}

// single-block exclusive scan of block sums (nb <= 1024)
__global__ void k_scan2(int* __restrict__ bsums, int nb) {
    __shared__ int s[1024];
    int i = threadIdx.x;
    int v = (i < nb) ? bsums[i] : 0;
    s[i] = v;
    __syncthreads();
    for (int off = 1; off < 1024; off <<= 1) {
        int t = (i >= (unsigned)off) ? s[i - off] : 0;
        __syncthreads();
        s[i] += t;
        __syncthreads();
    }
    if (i < nb) bsums[i] = s[i] - v;
}

__global__ void k_scan3(const int* __restrict__ excl, const int* __restrict__ bsums,
                        int* __restrict__ rowptr, int* __restrict__ cursor, int N, int E) {
    int i = blockIdx.x * 256 + threadIdx.x;
    if (i < N) {
        int v = excl[i] + bsums[blockIdx.x];
        rowptr[i] = v;
        cursor[i] = v;
    }
    if (i == 0) rowptr[N] = E;
}

__global__ void k_scatter(const int* __restrict__ esrc, const int* __restrict__ edst, int E,
                          int* __restrict__ cursor, int* __restrict__ csr_src) {
    int i = blockIdx.x * blockDim.x + threadIdx.x;
    if (i >= E) return;
    int p = atomicAdd(cursor + edst[i], 1);
    csr_src[p] = esrc[i];
}

// ---------------- Fused per-dst GAT aggregation: atomic-free ----------------
// 16 lanes per dst node; lane = output feature. Two passes over the dst's edges:
// pass 1 max, pass 2 exp/sum/accumulate. Self-loop (d,d) handled implicitly.
template <int FOUT, bool BIAS, bool RELU>
__global__ void k_gat_dst(const int* __restrict__ rowptr, const int* __restrict__ csr_src,
                          const float* __restrict__ asrc, const float* __restrict__ adst,
                          const float* __restrict__ h_t, const float* __restrict__ b,
                          float* __restrict__ out, int N) {
    int grp  = (blockIdx.x * blockDim.x + threadIdx.x) >> 4;
    int lane = threadIdx.x & 15;
    if (grp >= N) return;
    int d = grp;
    int r0 = rowptr[d], r1 = rowptr[d + 1];
    float ad = adst[d];
    float as_self = asrc[d];

    // pass 1: segment max (all 16 lanes compute identically; loads broadcast)
    float e0 = as_self + ad;
    e0 = (e0 >= 0.f) ? e0 : NEG_SLOPE * e0;
    float m = e0;
    for (int j = r0; j < r1; j++) {
        int s = csr_src[j];
        float e = asrc[s] + ad;
        e = (e >= 0.f) ? e : NEG_SLOPE * e;
        m = fmaxf(m, e);
    }

    // pass 2: p = exp(e-m); denom; acc_f += p * h_t[src][f]
    float sum = 0.f, acc = 0.f;
    {
        float p = __expf(e0 - m);
        sum += p;
        if (lane < FOUT) acc += p * h_t[(long long)d * FOUT + lane];
    }
    for (int j = r0; j < r1; j++) {
        int s = csr_src[j];
        float e = asrc[s] + ad;
        e = (e >= 0.f) ? e : NEG_SLOPE * e;
        float p = __expf(e - m);
        sum += p;
        if (lane < FOUT) acc += p * h_t[(long long)s * FOUT + lane];
    }

    if (lane < FOUT) {
        float v = acc / fmaxf(sum, 1e-16f);
        if (BIAS) v += b[lane];
        if (RELU) v = fmaxf(v, 0.f);
        out[(long long)d * FOUT + lane] = v;
    }
}

// ---------------- K6: pool + softmax ----------------
__global__ void k_pool(const float* __restrict__ h3, const int* __restrict__ batch,
                       const float* __restrict__ b3, float* __restrict__ out, int N, int C) {
    int g = blockIdx.x;
    int lo = 0, hi = N;
    while (lo < hi) { int mid = (lo + hi) >> 1; if (batch[mid] < g) lo = mid + 1; else hi = mid; }
    int start = lo;
    hi = N;
    while (lo < hi) { int mid = (lo + hi) >> 1; if (batch[mid] < g + 1) lo = mid + 1; else hi = mid; }
    int end = lo;

    float sum[16];
    for (int f = 0; f < C; f++) sum[f] = 0.f;
    for (int n = start + threadIdx.x; n < end; n += blockDim.x) {
        const float* r = h3 + (long long)n * C;
        for (int f = 0; f < C; f++) sum[f] += r[f];
    }
    __shared__ float red[256 * 16];
    for (int f = 0; f < C; f++) red[threadIdx.x * 16 + f] = sum[f];
    __syncthreads();
    for (int str = blockDim.x / 2; str > 0; str >>= 1) {
        if ((int)threadIdx.x < str)
            for (int f = 0; f < C; f++) red[threadIdx.x * 16 + f] += red[(threadIdx.x + str) * 16 + f];
        __syncthreads();
    }
    if (threadIdx.x == 0) {
        float cnt = fmaxf((float)(end - start), 1.f);
        float vals[16];
        float mx = -INFINITY;
        for (int f = 0; f < C; f++) { vals[f] = red[f] / cnt + b3[f]; mx = fmaxf(mx, vals[f]); }
        float se = 0.f;
        for (int f = 0; f < C; f++) { vals[f] = __expf(vals[f] - mx); se += vals[f]; }
        for (int f = 0; f < C; f++) out[(long long)g * C + f] = vals[f] / se;
    }
}

extern "C" void kernel_launch(void* const* d_in, const int* in_sizes, int n_in,
                              void* d_out, int out_size, void* d_ws, size_t ws_size,
                              hipStream_t stream) {
    const float* x    = (const float*)d_in[0];
    const int*   eidx = (const int*)d_in[1];
    const int*   batch= (const int*)d_in[2];
    const float* emb  = (const float*)d_in[3];
    const float* W1   = (const float*)d_in[4];
    const float* as1  = (const float*)d_in[5];
    const float* ad1  = (const float*)d_in[6];
    const float* b1   = (const float*)d_in[7];
    const float* W2   = (const float*)d_in[8];
    const float* as2  = (const float*)d_in[9];
    const float* ad2  = (const float*)d_in[10];
    const float* b2   = (const float*)d_in[11];
    const float* W3   = (const float*)d_in[12];
    const float* as3  = (const float*)d_in[13];
    const float* ad3  = (const float*)d_in[14];
    const float* b3   = (const float*)d_in[15];

    const int H = in_sizes[5];          // 16
    const int C = in_sizes[13];         // 10
    const int D = in_sizes[4] / H;      // 50
    const int V = in_sizes[3] / D;      // 128
    const int N = in_sizes[0] / V;      // 100000
    const int E = in_sizes[1] / 2;      // 1600000
    const int G = out_size / C;         // 512
    const int* esrc = eidx;
    const int* edst = eidx + E;

    char* w = (char*)d_ws;
    auto carve = [&](size_t bytes) {
        char* p = w;
        w += (bytes + 255) & ~(size_t)255;
        return p;
    };
    float* h0      = (float*)carve((size_t)N * D * 4);
    float* hT      = (float*)carve((size_t)N * H * 4);
    float* X0      = (float*)carve((size_t)N * H * 4);
    float* X1      = (float*)carve((size_t)N * H * 4);
    float* asrc    = (float*)carve((size_t)N * 4);
    float* adst    = (float*)carve((size_t)N * 4);
    int*   counts  = (int*)carve((size_t)N * 4);
    int*   excl    = (int*)carve((size_t)N * 4);
    int*   bsums   = (int*)carve(1024 * 4);
    int*   rowptr  = (int*)carve((size_t)(N + 1) * 4);
    int*   cursor  = (int*)carve((size_t)N * 4);
    int*   csr_src = (int*)carve((size_t)E * 4);
    (void)ws_size; (void)n_in;

    const int BT = 256;
    dim3 blk(BT);
    int gN   = (N + BT - 1) / BT;
    int gE   = (E + BT - 1) / BT;
    int gEmb = (N + 3) / 4;                 // 4 waves/block
    int gGat = (N * 16 + BT - 1) / BT;      // 16 lanes per dst
    int nb   = (N + 255) / 256;             // scan blocks (391 <= 1024)

    // ---- CSR build (once; reused by all 3 layers) ----
    hipMemsetAsync(counts, 0, (size_t)N * 4, stream);
    k_hist<<<gE, blk, 0, stream>>>(edst, E, counts);
    k_scan1<<<nb, blk, 0, stream>>>(counts, excl, bsums, N);
    k_scan2<<<1, 1024, 0, stream>>>(bsums, nb);
    k_scan3<<<nb, blk, 0, stream>>>(excl, bsums, rowptr, cursor, N, E);
    k_scatter<<<gE, blk, 0, stream>>>(esrc, edst, E, cursor, csr_src);

    // ---- K0: embedding ----
    k_embed<<<gEmb, blk, 0, stream>>>(x, emb, h0, N, V, D);

    // ---- layer 1: 50 -> 16, +b1, relu ----
    k_transform<50, 16><<<gN, blk, 0, stream>>>(h0, W1, as1, ad1, hT, asrc, adst, N);
    k_gat_dst<16, true, true><<<gGat, blk, 0, stream>>>(rowptr, csr_src, asrc, adst, hT, b1, X0, N);

    // ---- layer 2: 16 -> 16, +b2, relu ----
    k_transform<16, 16><<<gN, blk, 0, stream>>>(X0, W2, as2, ad2, hT, asrc, adst, N);
    k_gat_dst<16, true, true><<<gGat, blk, 0, stream>>>(rowptr, csr_src, asrc, adst, hT, b2, X1, N);

    // ---- layer 3: 16 -> 10, bias folded into pool ----
    k_transform<16, 10><<<gN, blk, 0, stream>>>(X1, W3, as3, ad3, hT, asrc, adst, N);
    k_gat_dst<10, false, false><<<gGat, blk, 0, stream>>>(rowptr, csr_src, asrc, adst, hT, nullptr, X0, N);

    // ---- pool + softmax ----
    k_pool<<<G, blk, 0, stream>>>(X0, batch, b3, (float*)d_out, N, C);
}

// Round 3
// 608.068 us; speedup vs baseline: 7.1357x; 1.0240x over previous
//
#include <hip/hip_runtime.h>
#include <math.h>

#define NEG_SLOPE 0.2f

// ---------------- K0: argmax over V features + embedding gather ----------------
__global__ void k_embed(const float* __restrict__ x, const float* __restrict__ emb,
                        float* __restrict__ h0, int N, int V, int D) {
    int wave = (blockIdx.x * blockDim.x + threadIdx.x) >> 6;
    int lane = threadIdx.x & 63;
    if (wave >= N) return;
    const float* row = x + (long long)wave * V;
    float bv = -INFINITY;
    int bi = 0x7fffffff;
    for (int j = lane; j < V; j += 64) {
        float v = row[j];
        if (v > bv || (v == bv && j < bi)) { bv = v; bi = j; }
    }
    for (int off = 32; off > 0; off >>= 1) {
        float ov = __shfl_down(bv, off, 64);
        int   oi = __shfl_down(bi, off, 64);
        if (ov > bv || (ov == bv && oi < bi)) { bv = ov; bi = oi; }
    }
    bi = __shfl(bi, 0, 64);
    const float* er = emb + (long long)bi * D;
    float* hr = h0 + (long long)wave * D;
    for (int f = lane; f < D; f += 64) hr[f] = er[f];
}

// ---------------- K1: dense transform + attention scalars ----------------
template <int FIN, int FOUT>
__global__ void k_transform(const float* __restrict__ h_in, const float* __restrict__ W,
                            const float* __restrict__ a_src, const float* __restrict__ a_dst,
                            float* __restrict__ h_t, float* __restrict__ asrc,
                            float* __restrict__ adst, int N) {
    __shared__ float sW[FIN * FOUT];
    __shared__ float sa[FOUT], sd[FOUT];
    for (int i = threadIdx.x; i < FIN * FOUT; i += blockDim.x) sW[i] = W[i];
    if (threadIdx.x < FOUT) { sa[threadIdx.x] = a_src[threadIdx.x]; sd[threadIdx.x] = a_dst[threadIdx.x]; }
    __syncthreads();
    int n = blockIdx.x * blockDim.x + threadIdx.x;
    if (n >= N) return;
    float acc[FOUT];
#pragma unroll
    for (int f = 0; f < FOUT; f++) acc[f] = 0.f;
    const float* hr = h_in + (long long)n * FIN;
    for (int k = 0; k < FIN; k++) {
        float v = hr[k];
#pragma unroll
        for (int f = 0; f < FOUT; f++) acc[f] += v * sW[k * FOUT + f];
    }
    float s1 = 0.f, s2 = 0.f;
    float* tr = h_t + (long long)n * FOUT;
#pragma unroll
    for (int f = 0; f < FOUT; f++) {
        tr[f] = acc[f];
        s1 += acc[f] * sa[f];
        s2 += acc[f] * sd[f];
    }
    asrc[n] = s1;
    adst[n] = s2;
}

// ---------------- CSR build (dst-grouped), write-dense two-phase ----------------
__global__ void k_hist(const int* __restrict__ edst, int E, int* __restrict__ counts) {
    int i = blockIdx.x * blockDim.x + threadIdx.x;
    if (i < E) atomicAdd(counts + edst[i], 1);
}

__global__ void k_scan1(const int* __restrict__ counts, int* __restrict__ excl,
                        int* __restrict__ bsums, int N) {
    __shared__ int s[256];
    int i = blockIdx.x * 256 + threadIdx.x;
    int v = (i < N) ? counts[i] : 0;
    s[threadIdx.x] = v;
    __syncthreads();
    for (int off = 1; off < 256; off <<= 1) {
        int t = (threadIdx.x >= (unsigned)off) ? s[threadIdx.x - off] : 0;
        __syncthreads();
        s[threadIdx.x] += t;
        __syncthreads();
    }
    if (i < N) excl[i] = s[threadIdx.x] - v;
    if (threadIdx.x == 255) bsums[blockIdx.x] = s[255];
}

__global__ void k_scan2(int* __restrict__ bsums, int nb) {
    __shared__ int s[1024];
    int i = threadIdx.x;
    int v = (i < nb) ? bsums[i] : 0;
    s[i] = v;
    __syncthreads();
    for (int off = 1; off < 1024; off <<= 1) {
        int t = (i >= (unsigned)off) ? s[i - off] : 0;
        __syncthreads();
        s[i] += t;
        __syncthreads();
    }
    if (i < nb) bsums[i] = s[i] - v;
}

__global__ void k_scan3(const int* __restrict__ excl, const int* __restrict__ bsums,
                        int* __restrict__ rowptr, int N, int E) {
    int i = blockIdx.x * 256 + threadIdx.x;
    if (i < N) rowptr[i] = excl[i] + bsums[blockIdx.x];
    if (i == 0) rowptr[N] = E;
}

// bucket cursors = rowptr at bucket boundaries (bucket = dst >> 6)
__global__ void k_binit(const int* __restrict__ rowptr, int* __restrict__ bcursor, int NB) {
    int i = blockIdx.x * blockDim.x + threadIdx.x;
    if (i < NB) bcursor[i] = rowptr[i << 6];
}

// Phase A: append packed (dst&63)<<18 | src into bucket region (write-dense)
__global__ void k_bucket(const int* __restrict__ esrc, const int* __restrict__ edst, int E,
                         int* __restrict__ bcursor, int* __restrict__ tmp) {
    int i = blockIdx.x * blockDim.x + threadIdx.x;
    if (i >= E) return;
    int d = edst[i];
    int pos = atomicAdd(bcursor + (d >> 6), 1);
    tmp[pos] = ((d & 63) << 18) | esrc[i];
}

// Phase B: one block per bucket; bin bucket entries to exact csr slots via LDS cursors.
__global__ void k_bin(const int* __restrict__ rowptr, const int* __restrict__ tmp,
                      int* __restrict__ csr_src, int N) {
    __shared__ int sc[64];
    int b = blockIdx.x;
    int d0 = b << 6;
    int dend = min(d0 + 64, N);
    if ((int)threadIdx.x < dend - d0) sc[threadIdx.x] = rowptr[d0 + threadIdx.x];
    __syncthreads();
    int t0 = rowptr[d0], t1 = rowptr[dend];
    for (int i = t0 + threadIdx.x; i < t1; i += blockDim.x) {
        int p = tmp[i];
        int pos = atomicAdd(&sc[p >> 18], 1);
        csr_src[pos] = p & 0x3FFFF;
    }
}

// ---------------- Fused per-dst GAT aggregation: single-pass online softmax ----------------
// 16 lanes per dst node; lane = output feature. Branchless online max-rescale.
template <int FOUT, bool BIAS, bool RELU>
__global__ void k_gat_dst(const int* __restrict__ rowptr, const int* __restrict__ csr_src,
                          const float* __restrict__ asrc, const float* __restrict__ adst,
                          const float* __restrict__ h_t, const float* __restrict__ b,
                          float* __restrict__ out, int N) {
    int grp  = (blockIdx.x * blockDim.x + threadIdx.x) >> 4;
    int lane = threadIdx.x & 15;
    if (grp >= N) return;
    int d = grp;
    int r0 = rowptr[d], r1 = rowptr[d + 1];
    float ad = adst[d];

    // self-loop seeds the online state: m = e_self, p_self = 1
    float e0 = asrc[d] + ad;
    e0 = (e0 >= 0.f) ? e0 : NEG_SLOPE * e0;
    float m = e0, sum = 1.f;
    float acc = (lane < FOUT) ? h_t[(long long)d * FOUT + lane] : 0.f;

    auto upd = [&](float a, float h) {
        float e = a + ad;
        e = (e >= 0.f) ? e : NEG_SLOPE * e;
        float mn = fmaxf(m, e);
        float pm = __expf(m - mn);
        float pe = __expf(e - mn);
        sum = sum * pm + pe;
        acc = acc * pm + pe * h;
        m = mn;
    };

    int j = r0;
    for (; j + 4 <= r1; j += 4) {
        int s0 = csr_src[j + 0], s1 = csr_src[j + 1];
        int s2 = csr_src[j + 2], s3 = csr_src[j + 3];
        float a0 = asrc[s0], a1 = asrc[s1], a2 = asrc[s2], a3 = asrc[s3];
        float h0 = 0.f, h1 = 0.f, h2 = 0.f, h3 = 0.f;
        if (lane < FOUT) {
            h0 = h_t[(long long)s0 * FOUT + lane];
            h1 = h_t[(long long)s1 * FOUT + lane];
            h2 = h_t[(long long)s2 * FOUT + lane];
            h3 = h_t[(long long)s3 * FOUT + lane];
        }
        upd(a0, h0); upd(a1, h1); upd(a2, h2); upd(a3, h3);
    }
    for (; j < r1; j++) {
        int s = csr_src[j];
        float a = asrc[s];
        float h = (lane < FOUT) ? h_t[(long long)s * FOUT + lane] : 0.f;
        upd(a, h);
    }

    if (lane < FOUT) {
        float v = acc / fmaxf(sum, 1e-16f);
        if (BIAS) v += b[lane];
        if (RELU) v = fmaxf(v, 0.f);
        out[(long long)d * FOUT + lane] = v;
    }
}

// ---------------- K6: pool + softmax ----------------
__global__ void k_pool(const float* __restrict__ h3, const int* __restrict__ batch,
                       const float* __restrict__ b3, float* __restrict__ out, int N, int C) {
    int g = blockIdx.x;
    int lo = 0, hi = N;
    while (lo < hi) { int mid = (lo + hi) >> 1; if (batch[mid] < g) lo = mid + 1; else hi = mid; }
    int start = lo;
    hi = N;
    while (lo < hi) { int mid = (lo + hi) >> 1; if (batch[mid] < g + 1) lo = mid + 1; else hi = mid; }
    int end = lo;

    float sum[16];
    for (int f = 0; f < C; f++) sum[f] = 0.f;
    for (int n = start + threadIdx.x; n < end; n += blockDim.x) {
        const float* r = h3 + (long long)n * C;
        for (int f = 0; f < C; f++) sum[f] += r[f];
    }
    __shared__ float red[256 * 16];
    for (int f = 0; f < C; f++) red[threadIdx.x * 16 + f] = sum[f];
    __syncthreads();
    for (int str = blockDim.x / 2; str > 0; str >>= 1) {
        if ((int)threadIdx.x < str)
            for (int f = 0; f < C; f++) red[threadIdx.x * 16 + f] += red[(threadIdx.x + str) * 16 + f];
        __syncthreads();
    }
    if (threadIdx.x == 0) {
        float cnt = fmaxf((float)(end - start), 1.f);
        float vals[16];
        float mx = -INFINITY;
        for (int f = 0; f < C; f++) { vals[f] = red[f] / cnt + b3[f]; mx = fmaxf(mx, vals[f]); }
        float se = 0.f;
        for (int f = 0; f < C; f++) { vals[f] = __expf(vals[f] - mx); se += vals[f]; }
        for (int f = 0; f < C; f++) out[(long long)g * C + f] = vals[f] / se;
    }
}

extern "C" void kernel_launch(void* const* d_in, const int* in_sizes, int n_in,
                              void* d_out, int out_size, void* d_ws, size_t ws_size,
                              hipStream_t stream) {
    const float* x    = (const float*)d_in[0];
    const int*   eidx = (const int*)d_in[1];
    const int*   batch= (const int*)d_in[2];
    const float* emb  = (const float*)d_in[3];
    const float* W1   = (const float*)d_in[4];
    const float* as1  = (const float*)d_in[5];
    const float* ad1  = (const float*)d_in[6];
    const float* b1   = (const float*)d_in[7];
    const float* W2   = (const float*)d_in[8];
    const float* as2  = (const float*)d_in[9];
    const float* ad2  = (const float*)d_in[10];
    const float* b2   = (const float*)d_in[11];
    const float* W3   = (const float*)d_in[12];
    const float* as3  = (const float*)d_in[13];
    const float* ad3  = (const float*)d_in[14];
    const float* b3   = (const float*)d_in[15];

    const int H = in_sizes[5];          // 16
    const int C = in_sizes[13];         // 10
    const int D = in_sizes[4] / H;      // 50
    const int V = in_sizes[3] / D;      // 128
    const int N = in_sizes[0] / V;      // 100000
    const int E = in_sizes[1] / 2;      // 1600000
    const int G = out_size / C;         // 512
    const int* esrc = eidx;
    const int* edst = eidx + E;

    char* w = (char*)d_ws;
    auto carve = [&](size_t bytes) {
        char* p = w;
        w += (bytes + 255) & ~(size_t)255;
        return p;
    };
    float* h0      = (float*)carve((size_t)N * D * 4);
    float* hT      = (float*)carve((size_t)N * H * 4);
    float* X0      = (float*)carve((size_t)N * H * 4);
    float* X1      = (float*)carve((size_t)N * H * 4);
    float* asrc    = (float*)carve((size_t)N * 4);
    float* adst    = (float*)carve((size_t)N * 4);
    int*   counts  = (int*)carve((size_t)N * 4);
    int*   excl    = (int*)carve((size_t)N * 4);
    int*   bsums   = (int*)carve(1024 * 4);
    int*   rowptr  = (int*)carve((size_t)(N + 1) * 4);
    int*   csr_src = (int*)carve((size_t)E * 4);
    int*   tmp     = (int*)carve((size_t)E * 4);
    const int NB   = (N + 63) >> 6;     // buckets of 64 dsts
    int*   bcursor = (int*)carve((size_t)NB * 4);
    (void)ws_size; (void)n_in;

    const int BT = 256;
    dim3 blk(BT);
    int gN   = (N + BT - 1) / BT;
    int gE   = (E + BT - 1) / BT;
    int gEmb = (N + 3) / 4;                 // 4 waves/block
    int gGat = (N * 16 + BT - 1) / BT;      // 16 lanes per dst
    int nb   = (N + 255) / 256;             // scan blocks (<=1024)

    // ---- CSR build (once; reused by all 3 layers) ----
    hipMemsetAsync(counts, 0, (size_t)N * 4, stream);
    k_hist<<<gE, blk, 0, stream>>>(edst, E, counts);
    k_scan1<<<nb, blk, 0, stream>>>(counts, excl, bsums, N);
    k_scan2<<<1, 1024, 0, stream>>>(bsums, nb);
    k_scan3<<<nb, blk, 0, stream>>>(excl, bsums, rowptr, N, E);
    k_binit<<<(NB + BT - 1) / BT, blk, 0, stream>>>(rowptr, bcursor, NB);
    k_bucket<<<gE, blk, 0, stream>>>(esrc, edst, E, bcursor, tmp);
    k_bin<<<NB, blk, 0, stream>>>(rowptr, tmp, csr_src, N);

    // ---- K0: embedding ----
    k_embed<<<gEmb, blk, 0, stream>>>(x, emb, h0, N, V, D);

    // ---- layer 1: 50 -> 16, +b1, relu ----
    k_transform<50, 16><<<gN, blk, 0, stream>>>(h0, W1, as1, ad1, hT, asrc, adst, N);
    k_gat_dst<16, true, true><<<gGat, blk, 0, stream>>>(rowptr, csr_src, asrc, adst, hT, b1, X0, N);

    // ---- layer 2: 16 -> 16, +b2, relu ----
    k_transform<16, 16><<<gN, blk, 0, stream>>>(X0, W2, as2, ad2, hT, asrc, adst, N);
    k_gat_dst<16, true, true><<<gGat, blk, 0, stream>>>(rowptr, csr_src, asrc, adst, hT, b2, X1, N);

    // ---- layer 3: 16 -> 10, bias folded into pool ----
    k_transform<16, 10><<<gN, blk, 0, stream>>>(X1, W3, as3, ad3, hT, asrc, adst, N);
    k_gat_dst<10, false, false><<<gGat, blk, 0, stream>>>(rowptr, csr_src, asrc, adst, hT, nullptr, X0, N);

    // ---- pool + softmax ----
    k_pool<<<G, blk, 0, stream>>>(X0, batch, b3, (float*)d_out, N, C);
}

// Round 4
// 434.488 us; speedup vs baseline: 9.9865x; 1.3995x over previous
//
#include <hip/hip_runtime.h>
#include <math.h>

#define NEG_SLOPE 0.2f

// ---------------- K0: argmax over V features + embedding gather ----------------
__global__ void k_embed(const float* __restrict__ x, const float* __restrict__ emb,
                        float* __restrict__ h0, int N, int V, int D) {
    int wave = (blockIdx.x * blockDim.x + threadIdx.x) >> 6;
    int lane = threadIdx.x & 63;
    if (wave >= N) return;
    const float* row = x + (long long)wave * V;
    float bv = -INFINITY;
    int bi = 0x7fffffff;
    for (int j = lane; j < V; j += 64) {
        float v = row[j];
        if (v > bv || (v == bv && j < bi)) { bv = v; bi = j; }
    }
    for (int off = 32; off > 0; off >>= 1) {
        float ov = __shfl_down(bv, off, 64);
        int   oi = __shfl_down(bi, off, 64);
        if (ov > bv || (ov == bv && oi < bi)) { bv = ov; bi = oi; }
    }
    bi = __shfl(bi, 0, 64);
    const float* er = emb + (long long)bi * D;
    float* hr = h0 + (long long)wave * D;
    for (int f = lane; f < D; f += 64) hr[f] = er[f];
}

// ---------------- K1: dense transform + attention scalars ----------------
template <int FIN, int FOUT>
__global__ void k_transform(const float* __restrict__ h_in, const float* __restrict__ W,
                            const float* __restrict__ a_src, const float* __restrict__ a_dst,
                            float* __restrict__ h_t, float* __restrict__ asrc,
                            float* __restrict__ adst, int N) {
    __shared__ float sW[FIN * FOUT];
    __shared__ float sa[FOUT], sd[FOUT];
    for (int i = threadIdx.x; i < FIN * FOUT; i += blockDim.x) sW[i] = W[i];
    if (threadIdx.x < FOUT) { sa[threadIdx.x] = a_src[threadIdx.x]; sd[threadIdx.x] = a_dst[threadIdx.x]; }
    __syncthreads();
    int n = blockIdx.x * blockDim.x + threadIdx.x;
    if (n >= N) return;
    float acc[FOUT];
#pragma unroll
    for (int f = 0; f < FOUT; f++) acc[f] = 0.f;
    const float* hr = h_in + (long long)n * FIN;
    for (int k = 0; k < FIN; k++) {
        float v = hr[k];
#pragma unroll
        for (int f = 0; f < FOUT; f++) acc[f] += v * sW[k * FOUT + f];
    }
    float s1 = 0.f, s2 = 0.f;
    float* tr = h_t + (long long)n * FOUT;
#pragma unroll
    for (int f = 0; f < FOUT; f++) {
        tr[f] = acc[f];
        s1 += acc[f] * sa[f];
        s2 += acc[f] * sd[f];
    }
    asrc[n] = s1;
    adst[n] = s2;
}

// ---------------- CSR build: XCD-replicated histogram + two-phase bucket scatter ----------------
// rep = blockIdx & 7 (round-robin block->XCD heuristic; perf-only, correctness independent).

// per-(rep,dst) histogram
__global__ void k_hist(const int* __restrict__ edst, int E, int* __restrict__ counts_r, int N) {
    int i = blockIdx.x * blockDim.x + threadIdx.x;
    if (i >= E) return;
    int rep = blockIdx.x & 7;
    atomicAdd(counts_r + (size_t)rep * N + edst[i], 1);
}

// scan over total per-dst counts (sum of 8 replicas)
__global__ void k_scan1(const int* __restrict__ counts_r, int* __restrict__ excl,
                        int* __restrict__ bsums, int N) {
    __shared__ int s[256];
    int i = blockIdx.x * 256 + threadIdx.x;
    int v = 0;
    if (i < N) {
#pragma unroll
        for (int r = 0; r < 8; r++) v += counts_r[(size_t)r * N + i];
    }
    s[threadIdx.x] = v;
    __syncthreads();
    for (int off = 1; off < 256; off <<= 1) {
        int t = (threadIdx.x >= (unsigned)off) ? s[threadIdx.x - off] : 0;
        __syncthreads();
        s[threadIdx.x] += t;
        __syncthreads();
    }
    if (i < N) excl[i] = s[threadIdx.x] - v;
    if (threadIdx.x == 255) bsums[blockIdx.x] = s[255];
}

__global__ void k_scan2(int* __restrict__ bsums, int nb) {
    __shared__ int s[1024];
    int i = threadIdx.x;
    int v = (i < nb) ? bsums[i] : 0;
    s[i] = v;
    __syncthreads();
    for (int off = 1; off < 1024; off <<= 1) {
        int t = (i >= (unsigned)off) ? s[i - off] : 0;
        __syncthreads();
        s[i] += t;
        __syncthreads();
    }
    if (i < nb) bsums[i] = s[i] - v;
}

__global__ void k_scan3(const int* __restrict__ excl, const int* __restrict__ bsums,
                        int* __restrict__ rowptr, int N, int E) {
    int i = blockIdx.x * 256 + threadIdx.x;
    if (i < N) rowptr[i] = excl[i] + bsums[blockIdx.x];
    if (i == 0) rowptr[N] = E;
}

// per-(bucket,rep) cursor bases: cur2[b*128 + r*16] (one counter per 64B line).
// base(b,r) = rowptr[b*64] + sum_{r'<r} sum_{d in bucket b} counts_r[r'][d]
__global__ void k_bcur(const int* __restrict__ counts_r, const int* __restrict__ rowptr,
                       int* __restrict__ cur2, int N) {
    int b = blockIdx.x;
    int lane = threadIdx.x;   // 64 threads
    int d0 = b << 6;
    int d = d0 + lane;
    int base = rowptr[min(d0, N)];
#pragma unroll
    for (int r = 0; r < 8; r++) {
        int v = (d < N) ? counts_r[(size_t)r * N + d] : 0;
        for (int off = 32; off > 0; off >>= 1) v += __shfl_down(v, off, 64);
        if (lane == 0) { cur2[b * 128 + r * 16] = base; base += v; }
        base = __shfl(base, 0, 64);
    }
}

// Phase A: append packed (dst&63)<<18 | src into this replica's subrange of the bucket.
__global__ void k_bucket(const int* __restrict__ esrc, const int* __restrict__ edst, int E,
                         int* __restrict__ cur2, int* __restrict__ tmp) {
    int i = blockIdx.x * blockDim.x + threadIdx.x;
    if (i >= E) return;
    int rep = blockIdx.x & 7;
    int d = edst[i];
    int pos = atomicAdd(cur2 + (d >> 6) * 128 + rep * 16, 1);
    tmp[pos] = ((d & 63) << 18) | esrc[i];
}

// Phase B: one block per bucket; bin entries to exact csr slots via LDS cursors.
__global__ void k_bin(const int* __restrict__ rowptr, const int* __restrict__ tmp,
                      int* __restrict__ csr_src, int N) {
    __shared__ int sc[64];
    int b = blockIdx.x;
    int d0 = b << 6;
    int dend = min(d0 + 64, N);
    if ((int)threadIdx.x < dend - d0) sc[threadIdx.x] = rowptr[d0 + threadIdx.x];
    __syncthreads();
    int t0 = rowptr[d0], t1 = rowptr[dend];
    for (int i = t0 + threadIdx.x; i < t1; i += blockDim.x) {
        int p = tmp[i];
        int pos = atomicAdd(&sc[p >> 18], 1);
        csr_src[pos] = p & 0x3FFFF;
    }
}

// ---------------- Fused per-dst GAT aggregation: single-pass online softmax ----------------
template <int FOUT, bool BIAS, bool RELU>
__global__ void k_gat_dst(const int* __restrict__ rowptr, const int* __restrict__ csr_src,
                          const float* __restrict__ asrc, const float* __restrict__ adst,
                          const float* __restrict__ h_t, const float* __restrict__ b,
                          float* __restrict__ out, int N) {
    int grp  = (blockIdx.x * blockDim.x + threadIdx.x) >> 4;
    int lane = threadIdx.x & 15;
    if (grp >= N) return;
    int d = grp;
    int r0 = rowptr[d], r1 = rowptr[d + 1];
    float ad = adst[d];

    float e0 = asrc[d] + ad;
    e0 = (e0 >= 0.f) ? e0 : NEG_SLOPE * e0;
    float m = e0, sum = 1.f;
    float acc = (lane < FOUT) ? h_t[(long long)d * FOUT + lane] : 0.f;

    auto upd = [&](float a, float h) {
        float e = a + ad;
        e = (e >= 0.f) ? e : NEG_SLOPE * e;
        float mn = fmaxf(m, e);
        float pm = __expf(m - mn);
        float pe = __expf(e - mn);
        sum = sum * pm + pe;
        acc = acc * pm + pe * h;
        m = mn;
    };

    int j = r0;
    for (; j + 4 <= r1; j += 4) {
        int s0 = csr_src[j + 0], s1 = csr_src[j + 1];
        int s2 = csr_src[j + 2], s3 = csr_src[j + 3];
        float a0 = asrc[s0], a1 = asrc[s1], a2 = asrc[s2], a3 = asrc[s3];
        float h0 = 0.f, h1 = 0.f, h2 = 0.f, h3 = 0.f;
        if (lane < FOUT) {
            h0 = h_t[(long long)s0 * FOUT + lane];
            h1 = h_t[(long long)s1 * FOUT + lane];
            h2 = h_t[(long long)s2 * FOUT + lane];
            h3 = h_t[(long long)s3 * FOUT + lane];
        }
        upd(a0, h0); upd(a1, h1); upd(a2, h2); upd(a3, h3);
    }
    for (; j < r1; j++) {
        int s = csr_src[j];
        float a = asrc[s];
        float h = (lane < FOUT) ? h_t[(long long)s * FOUT + lane] : 0.f;
        upd(a, h);
    }

    if (lane < FOUT) {
        float v = acc / fmaxf(sum, 1e-16f);
        if (BIAS) v += b[lane];
        if (RELU) v = fmaxf(v, 0.f);
        out[(long long)d * FOUT + lane] = v;
    }
}

// ---------------- K6: pool + softmax ----------------
__global__ void k_pool(const float* __restrict__ h3, const int* __restrict__ batch,
                       const float* __restrict__ b3, float* __restrict__ out, int N, int C) {
    int g = blockIdx.x;
    int lo = 0, hi = N;
    while (lo < hi) { int mid = (lo + hi) >> 1; if (batch[mid] < g) lo = mid + 1; else hi = mid; }
    int start = lo;
    hi = N;
    while (lo < hi) { int mid = (lo + hi) >> 1; if (batch[mid] < g + 1) lo = mid + 1; else hi = mid; }
    int end = lo;

    float sum[16];
    for (int f = 0; f < C; f++) sum[f] = 0.f;
    for (int n = start + threadIdx.x; n < end; n += blockDim.x) {
        const float* r = h3 + (long long)n * C;
        for (int f = 0; f < C; f++) sum[f] += r[f];
    }
    __shared__ float red[256 * 16];
    for (int f = 0; f < C; f++) red[threadIdx.x * 16 + f] = sum[f];
    __syncthreads();
    for (int str = blockDim.x / 2; str > 0; str >>= 1) {
        if ((int)threadIdx.x < str)
            for (int f = 0; f < C; f++) red[threadIdx.x * 16 + f] += red[(threadIdx.x + str) * 16 + f];
        __syncthreads();
    }
    if (threadIdx.x == 0) {
        float cnt = fmaxf((float)(end - start), 1.f);
        float vals[16];
        float mx = -INFINITY;
        for (int f = 0; f < C; f++) { vals[f] = red[f] / cnt + b3[f]; mx = fmaxf(mx, vals[f]); }
        float se = 0.f;
        for (int f = 0; f < C; f++) { vals[f] = __expf(vals[f] - mx); se += vals[f]; }
        for (int f = 0; f < C; f++) out[(long long)g * C + f] = vals[f] / se;
    }
}

extern "C" void kernel_launch(void* const* d_in, const int* in_sizes, int n_in,
                              void* d_out, int out_size, void* d_ws, size_t ws_size,
                              hipStream_t stream) {
    const float* x    = (const float*)d_in[0];
    const int*   eidx = (const int*)d_in[1];
    const int*   batch= (const int*)d_in[2];
    const float* emb  = (const float*)d_in[3];
    const float* W1   = (const float*)d_in[4];
    const float* as1  = (const float*)d_in[5];
    const float* ad1  = (const float*)d_in[6];
    const float* b1   = (const float*)d_in[7];
    const float* W2   = (const float*)d_in[8];
    const float* as2  = (const float*)d_in[9];
    const float* ad2  = (const float*)d_in[10];
    const float* b2   = (const float*)d_in[11];
    const float* W3   = (const float*)d_in[12];
    const float* as3  = (const float*)d_in[13];
    const float* ad3  = (const float*)d_in[14];
    const float* b3   = (const float*)d_in[15];

    const int H = in_sizes[5];          // 16
    const int C = in_sizes[13];         // 10
    const int D = in_sizes[4] / H;      // 50
    const int V = in_sizes[3] / D;      // 128
    const int N = in_sizes[0] / V;      // 100000
    const int E = in_sizes[1] / 2;      // 1600000
    const int G = out_size / C;         // 512
    const int* esrc = eidx;
    const int* edst = eidx + E;

    char* w = (char*)d_ws;
    auto carve = [&](size_t bytes) {
        char* p = w;
        w += (bytes + 255) & ~(size_t)255;
        return p;
    };
    float* h0       = (float*)carve((size_t)N * D * 4);
    float* hT       = (float*)carve((size_t)N * H * 4);
    float* X0       = (float*)carve((size_t)N * H * 4);
    float* X1       = (float*)carve((size_t)N * H * 4);
    float* asrc     = (float*)carve((size_t)N * 4);
    float* adst     = (float*)carve((size_t)N * 4);
    int*   counts_r = (int*)carve((size_t)8 * N * 4);
    int*   excl     = (int*)carve((size_t)N * 4);
    int*   bsums    = (int*)carve(1024 * 4);
    int*   rowptr   = (int*)carve((size_t)(N + 1) * 4);
    int*   csr_src  = (int*)carve((size_t)E * 4);
    int*   tmp      = (int*)carve((size_t)E * 4);
    const int NB    = (N + 63) >> 6;    // buckets of 64 dsts
    int*   cur2     = (int*)carve((size_t)NB * 128 * 4);  // [bucket][rep] padded to 64B
    (void)ws_size; (void)n_in;

    const int BT = 256;
    dim3 blk(BT);
    int gN   = (N + BT - 1) / BT;
    int gE   = (E + BT - 1) / BT;
    int gEmb = (N + 3) / 4;                 // 4 waves/block
    int gGat = (N * 16 + BT - 1) / BT;      // 16 lanes per dst
    int nb   = (N + 255) / 256;             // scan blocks (<=1024)

    // ---- CSR build (once; reused by all 3 layers) ----
    hipMemsetAsync(counts_r, 0, (size_t)8 * N * 4, stream);
    k_hist<<<gE, blk, 0, stream>>>(edst, E, counts_r, N);
    k_scan1<<<nb, blk, 0, stream>>>(counts_r, excl, bsums, N);
    k_scan2<<<1, 1024, 0, stream>>>(bsums, nb);
    k_scan3<<<nb, blk, 0, stream>>>(excl, bsums, rowptr, N, E);
    k_bcur<<<NB, 64, 0, stream>>>(counts_r, rowptr, cur2, N);
    k_bucket<<<gE, blk, 0, stream>>>(esrc, edst, E, cur2, tmp);
    k_bin<<<NB, blk, 0, stream>>>(rowptr, tmp, csr_src, N);

    // ---- K0: embedding ----
    k_embed<<<gEmb, blk, 0, stream>>>(x, emb, h0, N, V, D);

    // ---- layer 1: 50 -> 16, +b1, relu ----
    k_transform<50, 16><<<gN, blk, 0, stream>>>(h0, W1, as1, ad1, hT, asrc, adst, N);
    k_gat_dst<16, true, true><<<gGat, blk, 0, stream>>>(rowptr, csr_src, asrc, adst, hT, b1, X0, N);

    // ---- layer 2: 16 -> 16, +b2, relu ----
    k_transform<16, 16><<<gN, blk, 0, stream>>>(X0, W2, as2, ad2, hT, asrc, adst, N);
    k_gat_dst<16, true, true><<<gGat, blk, 0, stream>>>(rowptr, csr_src, asrc, adst, hT, b2, X1, N);

    // ---- layer 3: 16 -> 10, bias folded into pool ----
    k_transform<16, 10><<<gN, blk, 0, stream>>>(X1, W3, as3, ad3, hT, asrc, adst, N);
    k_gat_dst<10, false, false><<<gGat, blk, 0, stream>>>(rowptr, csr_src, asrc, adst, hT, nullptr, X0, N);

    // ---- pool + softmax ----
    k_pool<<<G, blk, 0, stream>>>(X0, batch, b3, (float*)d_out, N, C);
}